// Round 13
// baseline (383.950 us; speedup 1.0000x reference)
//
#include <hip/hip_runtime.h>

typedef unsigned short u16;
typedef _Float16 f16x8 __attribute__((ext_vector_type(8)));
typedef float f32x4 __attribute__((ext_vector_type(4)));

#define GLD16(gptr, lptr)                                                              \
  __builtin_amdgcn_global_load_lds((const __attribute__((address_space(1))) void*)(gptr), \
                                   (__attribute__((address_space(3))) void*)(lptr), 16, 0, 0)

#define MFMA_F16(a, b, c) __builtin_amdgcn_mfma_f32_16x16x32_f16((a), (b), (c), 0, 0, 0)

// ---------------- prep: transpose W1 [1024][2048] -> W1T [2048][1024], split fp16 hi/lo, swizzled ----
__global__ __launch_bounds__(256) void k_split_w1t(const float* __restrict__ w1,
                                                   u16* __restrict__ wh, u16* __restrict__ wl) {
  __shared__ float tile[32][33];
  int bn = blockIdx.x & 63;   // n tile (2048/32)
  int bk = blockIdx.x >> 6;   // k tile (1024/32)
  int tn = threadIdx.x & 31, tq = threadIdx.x >> 5;  // tq 0..7
#pragma unroll
  for (int r = 0; r < 4; ++r) {
    int k = bk * 32 + tq + r * 8;
    tile[tq + r * 8][tn] = w1[(size_t)k * 2048 + bn * 32 + tn];
  }
  __syncthreads();
#pragma unroll
  for (int r = 0; r < 4; ++r) {
    int n = bn * 32 + tq + r * 8;
    float v = tile[tn][tq + r * 8];
    _Float16 hi = (_Float16)v;
    _Float16 lo = (_Float16)(v - (float)hi);
    int qp = (tn >> 3) ^ ((n >> 1) & 3);
    int kp = bk * 32 + qp * 8 + (tn & 7);
    wh[(size_t)n * 1024 + kp] = __builtin_bit_cast(u16, hi);
    wl[(size_t)n * 1024 + kp] = __builtin_bit_cast(u16, lo);
  }
}

// ---------------- prep: W2g = g1*W2 in MFMA B-fragment order (16x16x32), split fp16 hi/lo ----------------
__global__ __launch_bounds__(256) void k_w2frag(const float* __restrict__ w2, const float* __restrict__ g1,
                                                u16* __restrict__ fh, u16* __restrict__ fl) {
  int t = blockIdx.x * 256 + threadIdx.x;  // 0..4095
  int c = t >> 6, l = t & 63;
  int col = l & 15, lg = l >> 4;
  f16x8 H, L;
#pragma unroll
  for (int j = 0; j < 8; ++j) {
    int k = c * 32 + lg * 8 + j;
    float v = (col < 9) ? g1[k] * w2[k * 9 + col] : 0.f;
    _Float16 hi = (_Float16)v;
    H[j] = hi;
    L[j] = (_Float16)(v - (float)hi);
  }
  *(f16x8*)(fh + (size_t)t * 8) = H;
  *(f16x8*)(fl + (size_t)t * 8) = L;
}

// ---------------- prep: cg[j] = sum_k g1[k]*W2[k][j], cb[j] = sum_k be1[k]*W2[k][j]  (f64) ----------------
__global__ void k_cgcb(const float* __restrict__ w2, const float* __restrict__ g1,
                       const float* __restrict__ be1, double* __restrict__ cgcb) {
  int l = threadIdx.x;  // 64 threads, 1 block
  double cg[9], cb[9];
#pragma unroll
  for (int j = 0; j < 9; ++j) { cg[j] = 0.0; cb[j] = 0.0; }
  for (int i = 0; i < 32; ++i) {
    int k = i * 64 + l;
    double g = (double)g1[k], b = (double)be1[k];
#pragma unroll
    for (int j = 0; j < 9; ++j) {
      double w = (double)w2[k * 9 + j];
      cg[j] += g * w;
      cb[j] += b * w;
    }
  }
  for (int off = 32; off; off >>= 1) {
#pragma unroll
    for (int j = 0; j < 9; ++j) {
      cg[j] += __shfl_xor(cg[j], off, 64);
      cb[j] += __shfl_xor(cb[j], off, 64);
    }
  }
  if (l == 0) {
    for (int j = 0; j < 16; ++j) {
      cgcb[j] = (j < 9) ? cg[j] : 0.0;
      cgcb[16 + j] = (j < 9) ? cb[j] : 0.0;
    }
  }
}

// ---------------- GEMM1 + fused GEMM2-partial: 3-term split-fp16, in-body reg-staged A split ----------------
// r12 structure + wave-parity-staggered cvt placement: even waves convert A(k+1) at clusters
// 1-2, odd waves at clusters 9-10 -> while one parity runs cvt (VALU), the other issues MFMA.
__global__ __launch_bounds__(512, 2) void k_gemm1(const float* __restrict__ x,
                                                  const u16* __restrict__ wh, const u16* __restrict__ wl,
                                                  const float* __restrict__ b1,
                                                  const u16* __restrict__ fh, const u16* __restrict__ fl,
                                                  float* __restrict__ pdot, float* __restrict__ pstat) {
  __shared__ __align__(16) u16 lds[2][4][8192];  // [buf][Ah,Al,Bh,Bl][256 rows * 32 k] = 128 KiB
  const int tid = threadIdx.x;
  // XCD swizzle (bijective, nwg=1024): per-XCD chunk covers 16 m-tiles x all 8 n-tiles
  const int swz = ((blockIdx.x & 7) << 7) | (blockIdx.x >> 3);
  const int m0 = (swz >> 3) << 8;
  const int n0 = (swz & 7) << 8;
  const int lane = tid & 63, w = tid >> 6;
  const int wr = (w >> 2) << 7;  // 0 or 128
  const int wc = (w & 3) << 6;   // 0,64,128,192
  const int lr = lane & 15, lg = lane >> 4;

  // tile-invariant LDS read offsets (u16 units), proven conflict-free swizzle (round-8)
  int a_off[8], b_off[4];
#pragma unroll
  for (int i = 0; i < 8; ++i) {
    int row = wr + i * 16 + lr;
    a_off[i] = row * 32 + ((lg ^ ((row >> 1) & 3)) << 3);
  }
#pragma unroll
  for (int j = 0; j < 4; ++j) {
    int row = wc + j * 16 + lr;
    b_off[j] = row * 32 + ((lg ^ ((row >> 1) & 3)) << 3);
  }

  // A reg-staging: thread owns LDS slot (row=tid>>2, q'=tid&3); loads global granule
  // q'^((row>>1)&3) so slot content matches the pre-swizzled layout (verified r11/r12).
  const size_t sxa_lo = (size_t)(m0 + (tid >> 2)) * 1024 + (size_t)(((tid & 3) ^ ((tid >> 3) & 3)) << 3);
  const size_t sxa_hi = sxa_lo + (size_t)128 * 1024;
  // B staging: 2 granules (16B) per thread per matrix; rows tid>>2 and tid>>2+128
  const size_t boff = (size_t)(n0 + (tid >> 2)) * 1024 + ((tid & 3) << 3);

#define STAGE_B(bf, mt, src, kk)                                          \
  do {                                                                    \
    GLD16((src) + boff + (kk), &lds[bf][mt][tid * 8]);                    \
    GLD16((src) + boff + 131072 + (kk), &lds[bf][mt][4096 + tid * 8]);    \
  } while (0)

#define LOAD_A(REG, kk)                                                   \
  do {                                                                    \
    REG[0] = *(const float4*)(x + sxa_lo + (kk));                         \
    REG[1] = *(const float4*)(x + sxa_lo + (kk) + 4);                     \
    REG[2] = *(const float4*)(x + sxa_hi + (kk));                         \
    REG[3] = *(const float4*)(x + sxa_hi + (kk) + 4);                     \
  } while (0)

#define CVT_LO(bf, REG)                                                   \
  do {                                                                    \
    float ff0[8] = {REG[0].x, REG[0].y, REG[0].z, REG[0].w,               \
                    REG[1].x, REG[1].y, REG[1].z, REG[1].w};              \
    f16x8 H0, L0;                                                         \
    _Pragma("unroll")                                                     \
    for (int e = 0; e < 8; ++e) {                                         \
      _Float16 h0 = (_Float16)ff0[e];                                     \
      H0[e] = h0;                                                         \
      L0[e] = (_Float16)(ff0[e] - (float)h0);                             \
    }                                                                     \
    *(f16x8*)&lds[bf][0][tid * 8] = H0;                                   \
    *(f16x8*)&lds[bf][1][tid * 8] = L0;                                   \
  } while (0)

#define CVT_HI(bf, REG)                                                   \
  do {                                                                    \
    float ff1[8] = {REG[2].x, REG[2].y, REG[2].z, REG[2].w,               \
                    REG[3].x, REG[3].y, REG[3].z, REG[3].w};              \
    f16x8 H1, L1;                                                         \
    _Pragma("unroll")                                                     \
    for (int e = 0; e < 8; ++e) {                                         \
      _Float16 h1 = (_Float16)ff1[e];                                     \
      H1[e] = h1;                                                         \
      L1[e] = (_Float16)(ff1[e] - (float)h1);                             \
    }                                                                     \
    *(f16x8*)&lds[bf][0][4096 + tid * 8] = H1;                            \
    *(f16x8*)&lds[bf][1][4096 + tid * 8] = L1;                            \
  } while (0)

  float4 regA[4], regB[4];

  // prologue: A(0)->regA -> cvt into buf0; A(1)->regB; B(0) staged into buf0
  LOAD_A(regA, 0);
  asm volatile("s_waitcnt vmcnt(0)" ::: "memory");
  CVT_LO(0, regA);
  CVT_HI(0, regA);
  LOAD_A(regB, 32);
  STAGE_B(0, 2, wh, 0);
  STAGE_B(0, 3, wl, 0);
  asm volatile("s_waitcnt lgkmcnt(0)" ::: "memory");  // cvt writes landed

  f32x4 acc[8][4] = {};

#define RD_B(CUR, j)                                      \
  do {                                                    \
    bhf[j] = *(const f16x8*)(&lds[CUR][2][0] + b_off[j]); \
    blf[j] = *(const f16x8*)(&lds[CUR][3][0] + b_off[j]); \
  } while (0)
#define RD_A(CUR, s, i)                                   \
  do {                                                    \
    ahf[s] = *(const f16x8*)(&lds[CUR][0][0] + a_off[i]); \
    alf[s] = *(const f16x8*)(&lds[CUR][1][0] + a_off[i]); \
  } while (0)
#define MM(s, i, j)                                       \
  do {                                                    \
    acc[i][j] = MFMA_F16(ahf[s], bhf[j], acc[i][j]);      \
    acc[i][j] = MFMA_F16(ahf[s], blf[j], acc[i][j]);      \
    acc[i][j] = MFMA_F16(alf[s], bhf[j], acc[i][j]);      \
  } while (0)
#define PRIO1 __builtin_amdgcn_s_setprio(1)
#define PRIO0 __builtin_amdgcn_s_setprio(0)

#define KBODY(KT, CUR, NXT, RLOAD, RCVT)                                            \
  do {                                                                              \
    const int nk1 = ((KT) + 1 < 32 ? (KT) + 1 : 31) * 32;                           \
    const int nk2 = ((KT) + 2 < 32 ? (KT) + 2 : 31) * 32;                           \
    asm volatile("s_waitcnt vmcnt(0)" ::: "memory"); /* all prefetch >=1 body old */\
    __builtin_amdgcn_s_barrier();                    /* buf[CUR] fully valid */     \
    asm volatile("" ::: "memory");                                                  \
    f16x8 bhf[4], blf[4], ahf[4], alf[4];                                           \
    RD_B(CUR, 0); RD_A(CUR, 0, 0);                                                  \
    PRIO1; MM(0, 0, 0); PRIO0;                                                      \
    RD_A(CUR, 1, 1);                                                                \
    if (!(w & 1)) CVT_LO(NXT, RCVT);                 /* even waves: cvt early */    \
    PRIO1; MM(1, 1, 0); PRIO0;                                                      \
    RD_B(CUR, 1);                                                                   \
    if (!(w & 1)) CVT_HI(NXT, RCVT);                                                \
    PRIO1; MM(0, 0, 1); MM(1, 1, 1); PRIO0;                                         \
    RD_A(CUR, 2, 2);                                                                \
    LOAD_A(RLOAD, nk2);                              /* A(KT+2) -> regs */          \
    PRIO1; MM(2, 2, 0); MM(2, 2, 1); PRIO0;                                         \
    RD_A(CUR, 3, 3);                                                                \
    PRIO1; MM(3, 3, 0); MM(3, 3, 1); PRIO0;                                         \
    RD_B(CUR, 2);                                                                   \
    STAGE_B(NXT, 2, wh, nk1);                                                       \
    PRIO1; MM(0, 0, 2); MM(1, 1, 2); MM(2, 2, 2); MM(3, 3, 2); PRIO0;               \
    RD_B(CUR, 3);                                                                   \
    STAGE_B(NXT, 3, wl, nk1);                                                       \
    PRIO1; MM(0, 0, 3); MM(1, 1, 3); MM(2, 2, 3); MM(3, 3, 3); PRIO0;               \
    RD_A(CUR, 0, 4);                                                                \
    PRIO1; MM(0, 4, 0); MM(0, 4, 1); MM(0, 4, 2); MM(0, 4, 3); PRIO0;               \
    RD_A(CUR, 1, 5);                                                                \
    if (w & 1) CVT_LO(NXT, RCVT);                    /* odd waves: cvt late */      \
    PRIO1; MM(1, 5, 0); MM(1, 5, 1); MM(1, 5, 2); MM(1, 5, 3); PRIO0;               \
    RD_A(CUR, 2, 6);                                                                \
    if (w & 1) CVT_HI(NXT, RCVT);                                                   \
    PRIO1; MM(2, 6, 0); MM(2, 6, 1); MM(2, 6, 2); MM(2, 6, 3); PRIO0;               \
    RD_A(CUR, 3, 7);                                                                \
    PRIO1; MM(3, 7, 0); MM(3, 7, 1); MM(3, 7, 2); MM(3, 7, 3); PRIO0;               \
    asm volatile("s_waitcnt lgkmcnt(0)" ::: "memory"); /* cvt writes done */        \
    asm volatile("" ::: "memory");                                                  \
    __builtin_amdgcn_s_barrier(); /* all waves done reading buf[CUR] */             \
  } while (0)

  for (int kt2 = 0; kt2 < 16; ++kt2) {
    KBODY(2 * kt2,     0, 1, regA, regB);  // even: cvt regB=A(odd) -> buf1, load A(k+2)->regA
    KBODY(2 * kt2 + 1, 1, 0, regB, regA);  // odd : cvt regA -> buf0,        load -> regB
  }
#undef KBODY
#undef RD_B
#undef RD_A
#undef MM
#undef PRIO1
#undef PRIO0
#undef STAGE_B
#undef LOAD_A
#undef CVT_LO
#undef CVT_HI

  // ======== fused epilogue: relu + GEMM2-partial + stats (no hbuf) ========
  asm volatile("s_waitcnt vmcnt(0)" ::: "memory");  // drain in-flight loads
  __syncthreads();                                  // LDS now free for reuse
  float* vt = (float*)&lds[0][0][0];                // [256 rows][128 cols f32], granule-swizzled

  // E0: bias + relu in place
#pragma unroll
  for (int j = 0; j < 4; ++j) {
    const float bias = b1[n0 + wc + j * 16 + lr];
#pragma unroll
    for (int i = 0; i < 8; ++i)
#pragma unroll
      for (int r = 0; r < 4; ++r) acc[i][j][r] = fmaxf(acc[i][j][r] + bias, 0.f);
  }

  f32x4 acc2[2] = {};
  float sstat[2] = {0.f, 0.f}, qstat[2] = {0.f, 0.f};
  const int myrow0 = w * 32;  // reader rows: [w*32, w*32+32)

#pragma unroll
  for (int half = 0; half < 2; ++half) {
    // write phase: waves with (w&3)>>1 == half own cols [half*128, half*128+128)
    if (((w & 3) >> 1) == half) {
      const int colbase = wc & 127;
#pragma unroll
      for (int j = 0; j < 4; ++j) {
        const int lcol = colbase + j * 16 + lr;
        const int g = lcol >> 2, wsel = lcol & 3;
#pragma unroll
        for (int i = 0; i < 8; ++i)
#pragma unroll
          for (int r = 0; r < 4; ++r) {
            const int row = wr + i * 16 + lg * 4 + r;
            vt[row * 128 + ((g ^ (row & 7)) << 2) + wsel] = acc[i][j][r];
          }
      }
    }
    __syncthreads();
    // read phase: 4 k-blocks of 32 cols
#pragma unroll
    for (int cl = 0; cl < 4; ++cl) {
      const int cglob = (n0 >> 5) + half * 4 + cl;
      const f16x8 bh = *(const f16x8*)(fh + (size_t)(cglob * 64 + lane) * 8);
      const f16x8 bl = *(const f16x8*)(fl + (size_t)(cglob * 64 + lane) * 8);
#pragma unroll
      for (int g2 = 0; g2 < 2; ++g2) {
        const int row = myrow0 + g2 * 16 + lr;
        const int g0 = cl * 8 + lg * 2;
        const float4 f0 = *(const float4*)&vt[row * 128 + ((g0 ^ (row & 7)) << 2)];
        const float4 f1 = *(const float4*)&vt[row * 128 + (((g0 + 1) ^ (row & 7)) << 2)];
        float f[8] = {f0.x, f0.y, f0.z, f0.w, f1.x, f1.y, f1.z, f1.w};
        f16x8 AH, AL;
#pragma unroll
        for (int e = 0; e < 8; ++e) {
          sstat[g2] += f[e];
          qstat[g2] = fmaf(f[e], f[e], qstat[g2]);
          _Float16 hi = (_Float16)f[e];
          AH[e] = hi;
          AL[e] = (_Float16)(f[e] - (float)hi);
        }
        acc2[g2] = MFMA_F16(AH, bh, acc2[g2]);
        acc2[g2] = MFMA_F16(AH, bl, acc2[g2]);
        acc2[g2] = MFMA_F16(AL, bh, acc2[g2]);
      }
    }
    __syncthreads();
  }

  // stats reduce over the 4 lg-lanes (same lr = same row)
#pragma unroll
  for (int g2 = 0; g2 < 2; ++g2) {
    sstat[g2] += __shfl_xor(sstat[g2], 16, 64);
    sstat[g2] += __shfl_xor(sstat[g2], 32, 64);
    qstat[g2] += __shfl_xor(qstat[g2], 16, 64);
    qstat[g2] += __shfl_xor(qstat[g2], 32, 64);
  }
  const int ntile = n0 >> 8;
#pragma unroll
  for (int g2 = 0; g2 < 2; ++g2) {
    if (lg == 0) {
      const int row = m0 + myrow0 + g2 * 16 + lr;
      *(float2*)&pstat[((size_t)row * 8 + ntile) * 2] = make_float2(sstat[g2], qstat[g2]);
    }
    if (lr < 9) {
#pragma unroll
      for (int r = 0; r < 4; ++r) {
        const int row = m0 + myrow0 + g2 * 16 + lg * 4 + r;
        pdot[((size_t)row * 8 + ntile) * 12 + lr] = acc2[g2][r];
      }
    }
  }
}

// ---------------- f64 3x3 SVD -> nearest SO(3) rotation ----------------
static __device__ __forceinline__ void jrot(double S[3][3], double V[3][3], int p, int q, int r) {
  double apq = S[p][q];
  if (apq == 0.0) return;
  double tau = (S[q][q] - S[p][p]) / (2.0 * apq);
  double t = (tau >= 0.0 ? 1.0 : -1.0) / (fabs(tau) + sqrt(1.0 + tau * tau));
  double c = 1.0 / sqrt(1.0 + t * t);
  double s = t * c;
  double spp = S[p][p], sqq = S[q][q];
  double srp = S[r][p], srq = S[r][q];
  S[p][p] = spp - t * apq;
  S[q][q] = sqq + t * apq;
  S[p][q] = 0.0; S[q][p] = 0.0;
  S[r][p] = c * srp - s * srq; S[p][r] = S[r][p];
  S[r][q] = s * srp + c * srq; S[q][r] = S[r][q];
#pragma unroll
  for (int i = 0; i < 3; ++i) {
    double vip = V[i][p], viq = V[i][q];
    V[i][p] = c * vip - s * viq;
    V[i][q] = s * vip + c * viq;
  }
}

static __device__ void svd_so3(const double* Rf, float* Of) {
  double A[3][3], S[3][3];
  double V[3][3] = {{1, 0, 0}, {0, 1, 0}, {0, 0, 1}};
#pragma unroll
  for (int i = 0; i < 3; ++i)
#pragma unroll
    for (int j = 0; j < 3; ++j) A[i][j] = Rf[i * 3 + j];
#pragma unroll
  for (int p = 0; p < 3; ++p)
#pragma unroll
    for (int q = 0; q < 3; ++q) {
      double sa = 0.0;
#pragma unroll
      for (int i = 0; i < 3; ++i) sa += A[i][p] * A[i][q];
      S[p][q] = sa;
    }
  for (int it = 0; it < 6; ++it) {
    jrot(S, V, 0, 1, 2);
    jrot(S, V, 0, 2, 1);
    jrot(S, V, 1, 2, 0);
  }
  double l0 = S[0][0], l1 = S[1][1], l2 = S[2][2];
  double c0[3] = {V[0][0], V[1][0], V[2][0]};
  double c1[3] = {V[0][1], V[1][1], V[2][1]};
  double c2[3] = {V[0][2], V[1][2], V[2][2]};
  double tl, tv;
#define SWP(la, lb, ca, cb)                                         \
  if (la < lb) {                                                    \
    tl = la; la = lb; lb = tl;                                      \
    tv = ca[0]; ca[0] = cb[0]; cb[0] = tv;                          \
    tv = ca[1]; ca[1] = cb[1]; cb[1] = tv;                          \
    tv = ca[2]; ca[2] = cb[2]; cb[2] = tv;                          \
  }
  SWP(l0, l1, c0, c1)
  SWP(l0, l2, c0, c2)
  SWP(l1, l2, c1, c2)
#undef SWP
  double v3[3];
  v3[0] = c0[1] * c1[2] - c0[2] * c1[1];
  v3[1] = c0[2] * c1[0] - c0[0] * c1[2];
  v3[2] = c0[0] * c1[1] - c0[1] * c1[0];
  double t1[3], t2[3];
#pragma unroll
  for (int i = 0; i < 3; ++i) {
    t1[i] = A[i][0] * c0[0] + A[i][1] * c0[1] + A[i][2] * c0[2];
    t2[i] = A[i][0] * c1[0] + A[i][1] * c1[1] + A[i][2] * c1[2];
  }
  double n1 = sqrt(t1[0] * t1[0] + t1[1] * t1[1] + t1[2] * t1[2]);
  if (n1 < 1e-20) {
#pragma unroll
    for (int t = 0; t < 9; ++t) Of[t] = (t == 0 || t == 4 || t == 8) ? 1.f : 0.f;
    return;
  }
  double u1[3], u2[3], u3[3];
  double r1 = 1.0 / n1;
#pragma unroll
  for (int i = 0; i < 3; ++i) u1[i] = t1[i] * r1;
  double d12 = u1[0] * t2[0] + u1[1] * t2[1] + u1[2] * t2[2];
#pragma unroll
  for (int i = 0; i < 3; ++i) t2[i] -= d12 * u1[i];
  double n2 = sqrt(t2[0] * t2[0] + t2[1] * t2[1] + t2[2] * t2[2]);
  if (n2 > 1e-14 * n1) {
    double r2 = 1.0 / n2;
#pragma unroll
    for (int i = 0; i < 3; ++i) u2[i] = t2[i] * r2;
  } else {
    double ax = fabs(u1[0]), ay = fabs(u1[1]), az = fabs(u1[2]);
    double e[3] = {0.0, 0.0, 0.0};
    if (ax <= ay && ax <= az) e[0] = 1.0;
    else if (ay <= az) e[1] = 1.0;
    else e[2] = 1.0;
    double d = e[0] * u1[0] + e[1] * u1[1] + e[2] * u1[2];
#pragma unroll
    for (int i = 0; i < 3; ++i) e[i] -= d * u1[i];
    double nn = 1.0 / sqrt(e[0] * e[0] + e[1] * e[1] + e[2] * e[2]);
#pragma unroll
    for (int i = 0; i < 3; ++i) u2[i] = e[i] * nn;
  }
  u3[0] = u1[1] * u2[2] - u1[2] * u2[1];
  u3[1] = u1[2] * u2[0] - u1[0] * u2[2];
  u3[2] = u1[0] * u2[1] - u1[1] * u2[0];
#pragma unroll
  for (int i = 0; i < 3; ++i)
#pragma unroll
    for (int j = 0; j < 3; ++j)
      Of[i * 3 + j] = (float)(u1[i] * c0[j] + u2[i] * c1[j] + u3[i] * v3[j]);
}

// ---------------- combine: f64 sum of partials + LN1-fold + LN2 + SVD, 1 thread/row ----------------
__global__ __launch_bounds__(256) void k_comb(const float* __restrict__ pdot,
                                              const float* __restrict__ pstat,
                                              const double* __restrict__ cgcb,
                                              const float* __restrict__ b2,
                                              const float* __restrict__ g2v,
                                              const float* __restrict__ be2,
                                              float* __restrict__ out) {
  const int row = blockIdx.x * 256 + threadIdx.x;
  double dj[9];
#pragma unroll
  for (int j = 0; j < 9; ++j) dj[j] = 0.0;
  double s = 0.0, q = 0.0;
#pragma unroll
  for (int nt = 0; nt < 8; ++nt) {
    const float* p = pdot + ((size_t)row * 8 + nt) * 12;
#pragma unroll
    for (int j = 0; j < 9; ++j) dj[j] += (double)p[j];
    const float* ps = pstat + ((size_t)row * 8 + nt) * 2;
    s += (double)ps[0];
    q += (double)ps[1];
  }
  const double mean = s * (1.0 / 2048.0);
  const double varr = fmax(q * (1.0 / 2048.0) - mean * mean, 0.0);
  const double inv = 1.0 / sqrt(varr + 1e-5);
  double a2[9];
  double s9 = 0.0, q9 = 0.0;
#pragma unroll
  for (int j = 0; j < 9; ++j) {
    double v = inv * (dj[j] - mean * cgcb[j]) + cgcb[16 + j] + (double)b2[j];
    v = fmax(v, 0.0);
    a2[j] = v;
    s9 += v;
    q9 += v * v;
  }
  const double m2 = s9 * (1.0 / 9.0);
  const double v2c = fmax(q9 * (1.0 / 9.0) - m2 * m2, 0.0);
  const double i2 = 1.0 / sqrt(v2c + 1e-5);
  double rn[9];
#pragma unroll
  for (int j = 0; j < 9; ++j) rn[j] = (a2[j] - m2) * i2 * (double)g2v[j] + (double)be2[j];
  float O[9];
  svd_so3(rn, O);
  float* op = out + (size_t)row * 9;
#pragma unroll
  for (int t = 0; t < 9; ++t) op[t] = O[t];
}

// ---------------- host ----------------
extern "C" void kernel_launch(void* const* d_in, const int* in_sizes, int n_in,
                              void* d_out, int out_size, void* d_ws, size_t ws_size,
                              hipStream_t stream) {
  const float* x   = (const float*)d_in[0];
  const float* W1  = (const float*)d_in[1];
  const float* b1  = (const float*)d_in[2];
  const float* g1  = (const float*)d_in[3];
  const float* be1 = (const float*)d_in[4];
  const float* W2  = (const float*)d_in[5];
  const float* b2  = (const float*)d_in[6];
  const float* g2  = (const float*)d_in[7];
  const float* be2 = (const float*)d_in[8];
  float* out = (float*)d_out;
  char* ws = (char*)d_ws;
  u16*    wh   = (u16*)(ws + 0);             // 4194304
  u16*    wl   = (u16*)(ws + 4194304);       // 4194304
  u16*    fh   = (u16*)(ws + 8388608);       // 65536
  u16*    fl   = (u16*)(ws + 8454144);       // 65536
  double* cgcb = (double*)(ws + 8519680);    // 256 B
  float*  pdot = (float*)(ws + 8519936);     // 32768*8*12*4 = 12582912
  float*  pstat= (float*)(ws + 21102848);    // 32768*8*2*4  = 2097152

  k_split_w1t<<<dim3(2048), dim3(256), 0, stream>>>(W1, wh, wl);
  k_w2frag<<<dim3(16), dim3(256), 0, stream>>>(W2, g1, fh, fl);
  k_cgcb<<<dim3(1), dim3(64), 0, stream>>>(W2, g1, be1, cgcb);
  k_gemm1<<<dim3(1024), dim3(512), 0, stream>>>(x, wh, wl, b1, fh, fl, pdot, pstat);
  k_comb<<<dim3(128), dim3(256), 0, stream>>>(pdot, pstat, cgcb, b2, g2, be2, out);
}

// Round 14
// 377.816 us; speedup vs baseline: 1.0162x; 1.0162x over previous
//
#include <hip/hip_runtime.h>

typedef unsigned short u16;
typedef _Float16 f16x8 __attribute__((ext_vector_type(8)));
typedef float f32x4 __attribute__((ext_vector_type(4)));

#define GLD16(gptr, lptr)                                                              \
  __builtin_amdgcn_global_load_lds((const __attribute__((address_space(1))) void*)(gptr), \
                                   (__attribute__((address_space(3))) void*)(lptr), 16, 0, 0)

#define MFMA_F16(a, b, c) __builtin_amdgcn_mfma_f32_16x16x32_f16((a), (b), (c), 0, 0, 0)

// ---------------- prep: transpose W1 [1024][2048] -> W1T [2048][1024], split fp16 hi/lo, swizzled ----
__global__ __launch_bounds__(256) void k_split_w1t(const float* __restrict__ w1,
                                                   u16* __restrict__ wh, u16* __restrict__ wl) {
  __shared__ float tile[32][33];
  int bn = blockIdx.x & 63;   // n tile (2048/32)
  int bk = blockIdx.x >> 6;   // k tile (1024/32)
  int tn = threadIdx.x & 31, tq = threadIdx.x >> 5;  // tq 0..7
#pragma unroll
  for (int r = 0; r < 4; ++r) {
    int k = bk * 32 + tq + r * 8;
    tile[tq + r * 8][tn] = w1[(size_t)k * 2048 + bn * 32 + tn];
  }
  __syncthreads();
#pragma unroll
  for (int r = 0; r < 4; ++r) {
    int n = bn * 32 + tq + r * 8;
    float v = tile[tn][tq + r * 8];
    _Float16 hi = (_Float16)v;
    _Float16 lo = (_Float16)(v - (float)hi);
    int qp = (tn >> 3) ^ ((n >> 1) & 3);
    int kp = bk * 32 + qp * 8 + (tn & 7);
    wh[(size_t)n * 1024 + kp] = __builtin_bit_cast(u16, hi);
    wl[(size_t)n * 1024 + kp] = __builtin_bit_cast(u16, lo);
  }
}

// ---------------- prep: W2g = g1*W2 in MFMA B-fragment order (16x16x32), split fp16 hi/lo ----------------
__global__ __launch_bounds__(256) void k_w2frag(const float* __restrict__ w2, const float* __restrict__ g1,
                                                u16* __restrict__ fh, u16* __restrict__ fl) {
  int t = blockIdx.x * 256 + threadIdx.x;  // 0..4095
  int c = t >> 6, l = t & 63;
  int col = l & 15, lg = l >> 4;
  f16x8 H, L;
#pragma unroll
  for (int j = 0; j < 8; ++j) {
    int k = c * 32 + lg * 8 + j;
    float v = (col < 9) ? g1[k] * w2[k * 9 + col] : 0.f;
    _Float16 hi = (_Float16)v;
    H[j] = hi;
    L[j] = (_Float16)(v - (float)hi);
  }
  *(f16x8*)(fh + (size_t)t * 8) = H;
  *(f16x8*)(fl + (size_t)t * 8) = L;
}

// ---------------- prep: cg[j] = sum_k g1[k]*W2[k][j], cb[j] = sum_k be1[k]*W2[k][j]  (f64) ----------------
__global__ void k_cgcb(const float* __restrict__ w2, const float* __restrict__ g1,
                       const float* __restrict__ be1, double* __restrict__ cgcb) {
  int l = threadIdx.x;  // 64 threads, 1 block
  double cg[9], cb[9];
#pragma unroll
  for (int j = 0; j < 9; ++j) { cg[j] = 0.0; cb[j] = 0.0; }
  for (int i = 0; i < 32; ++i) {
    int k = i * 64 + l;
    double g = (double)g1[k], b = (double)be1[k];
#pragma unroll
    for (int j = 0; j < 9; ++j) {
      double w = (double)w2[k * 9 + j];
      cg[j] += g * w;
      cb[j] += b * w;
    }
  }
  for (int off = 32; off; off >>= 1) {
#pragma unroll
    for (int j = 0; j < 9; ++j) {
      cg[j] += __shfl_xor(cg[j], off, 64);
      cb[j] += __shfl_xor(cb[j], off, 64);
    }
  }
  if (l == 0) {
    for (int j = 0; j < 16; ++j) {
      cgcb[j] = (j < 9) ? cg[j] : 0.0;
      cgcb[16 + j] = (j < 9) ? cb[j] : 0.0;
    }
  }
}

// ---------------- GEMM1 + fused GEMM2-partial: 3-term split-fp16, in-body reg-staged A split ----------------
// r12 structure (measured best, 379.0 us): entry vmcnt(0)+barrier; in-body cvt+ds_write of
// A(k+1) at clusters 1-2 (all waves); A(k+2)/B(k+1) loads issued mid-body; 2 barriers/tile.
__global__ __launch_bounds__(512, 2) void k_gemm1(const float* __restrict__ x,
                                                  const u16* __restrict__ wh, const u16* __restrict__ wl,
                                                  const float* __restrict__ b1,
                                                  const u16* __restrict__ fh, const u16* __restrict__ fl,
                                                  float* __restrict__ pdot, float* __restrict__ pstat) {
  __shared__ __align__(16) u16 lds[2][4][8192];  // [buf][Ah,Al,Bh,Bl][256 rows * 32 k] = 128 KiB
  const int tid = threadIdx.x;
  // XCD swizzle (bijective, nwg=1024): per-XCD chunk covers 16 m-tiles x all 8 n-tiles
  const int swz = ((blockIdx.x & 7) << 7) | (blockIdx.x >> 3);
  const int m0 = (swz >> 3) << 8;
  const int n0 = (swz & 7) << 8;
  const int lane = tid & 63, w = tid >> 6;
  const int wr = (w >> 2) << 7;  // 0 or 128
  const int wc = (w & 3) << 6;   // 0,64,128,192
  const int lr = lane & 15, lg = lane >> 4;

  // tile-invariant LDS read offsets (u16 units), proven conflict-free swizzle (round-8)
  int a_off[8], b_off[4];
#pragma unroll
  for (int i = 0; i < 8; ++i) {
    int row = wr + i * 16 + lr;
    a_off[i] = row * 32 + ((lg ^ ((row >> 1) & 3)) << 3);
  }
#pragma unroll
  for (int j = 0; j < 4; ++j) {
    int row = wc + j * 16 + lr;
    b_off[j] = row * 32 + ((lg ^ ((row >> 1) & 3)) << 3);
  }

  // A reg-staging: thread owns LDS slot (row=tid>>2, q'=tid&3); loads global granule
  // q'^((row>>1)&3) so slot content matches the pre-swizzled layout (verified r11/r12).
  const size_t sxa_lo = (size_t)(m0 + (tid >> 2)) * 1024 + (size_t)(((tid & 3) ^ ((tid >> 3) & 3)) << 3);
  const size_t sxa_hi = sxa_lo + (size_t)128 * 1024;
  // B staging: 2 granules (16B) per thread per matrix; rows tid>>2 and tid>>2+128
  const size_t boff = (size_t)(n0 + (tid >> 2)) * 1024 + ((tid & 3) << 3);

#define STAGE_B(bf, mt, src, kk)                                          \
  do {                                                                    \
    GLD16((src) + boff + (kk), &lds[bf][mt][tid * 8]);                    \
    GLD16((src) + boff + 131072 + (kk), &lds[bf][mt][4096 + tid * 8]);    \
  } while (0)

#define LOAD_A(REG, kk)                                                   \
  do {                                                                    \
    REG[0] = *(const float4*)(x + sxa_lo + (kk));                         \
    REG[1] = *(const float4*)(x + sxa_lo + (kk) + 4);                     \
    REG[2] = *(const float4*)(x + sxa_hi + (kk));                         \
    REG[3] = *(const float4*)(x + sxa_hi + (kk) + 4);                     \
  } while (0)

#define CVT_LO(bf, REG)                                                   \
  do {                                                                    \
    float ff0[8] = {REG[0].x, REG[0].y, REG[0].z, REG[0].w,               \
                    REG[1].x, REG[1].y, REG[1].z, REG[1].w};              \
    f16x8 H0, L0;                                                         \
    _Pragma("unroll")                                                     \
    for (int e = 0; e < 8; ++e) {                                         \
      _Float16 h0 = (_Float16)ff0[e];                                     \
      H0[e] = h0;                                                         \
      L0[e] = (_Float16)(ff0[e] - (float)h0);                             \
    }                                                                     \
    *(f16x8*)&lds[bf][0][tid * 8] = H0;                                   \
    *(f16x8*)&lds[bf][1][tid * 8] = L0;                                   \
  } while (0)

#define CVT_HI(bf, REG)                                                   \
  do {                                                                    \
    float ff1[8] = {REG[2].x, REG[2].y, REG[2].z, REG[2].w,               \
                    REG[3].x, REG[3].y, REG[3].z, REG[3].w};              \
    f16x8 H1, L1;                                                         \
    _Pragma("unroll")                                                     \
    for (int e = 0; e < 8; ++e) {                                         \
      _Float16 h1 = (_Float16)ff1[e];                                     \
      H1[e] = h1;                                                         \
      L1[e] = (_Float16)(ff1[e] - (float)h1);                             \
    }                                                                     \
    *(f16x8*)&lds[bf][0][4096 + tid * 8] = H1;                            \
    *(f16x8*)&lds[bf][1][4096 + tid * 8] = L1;                            \
  } while (0)

  float4 regA[4], regB[4];

  // prologue: A(0)->regA -> cvt into buf0; A(1)->regB; B(0) staged into buf0
  LOAD_A(regA, 0);
  asm volatile("s_waitcnt vmcnt(0)" ::: "memory");
  CVT_LO(0, regA);
  CVT_HI(0, regA);
  LOAD_A(regB, 32);
  STAGE_B(0, 2, wh, 0);
  STAGE_B(0, 3, wl, 0);
  asm volatile("s_waitcnt lgkmcnt(0)" ::: "memory");  // cvt writes landed

  f32x4 acc[8][4] = {};

#define RD_B(CUR, j)                                      \
  do {                                                    \
    bhf[j] = *(const f16x8*)(&lds[CUR][2][0] + b_off[j]); \
    blf[j] = *(const f16x8*)(&lds[CUR][3][0] + b_off[j]); \
  } while (0)
#define RD_A(CUR, s, i)                                   \
  do {                                                    \
    ahf[s] = *(const f16x8*)(&lds[CUR][0][0] + a_off[i]); \
    alf[s] = *(const f16x8*)(&lds[CUR][1][0] + a_off[i]); \
  } while (0)
#define MM(s, i, j)                                       \
  do {                                                    \
    acc[i][j] = MFMA_F16(ahf[s], bhf[j], acc[i][j]);      \
    acc[i][j] = MFMA_F16(ahf[s], blf[j], acc[i][j]);      \
    acc[i][j] = MFMA_F16(alf[s], bhf[j], acc[i][j]);      \
  } while (0)
#define PRIO1 __builtin_amdgcn_s_setprio(1)
#define PRIO0 __builtin_amdgcn_s_setprio(0)

#define KBODY(KT, CUR, NXT, RLOAD, RCVT)                                            \
  do {                                                                              \
    const int nk1 = ((KT) + 1 < 32 ? (KT) + 1 : 31) * 32;                           \
    const int nk2 = ((KT) + 2 < 32 ? (KT) + 2 : 31) * 32;                           \
    asm volatile("s_waitcnt vmcnt(0)" ::: "memory"); /* all prefetch >=1 body old */\
    __builtin_amdgcn_s_barrier();                    /* buf[CUR] fully valid */     \
    asm volatile("" ::: "memory");                                                  \
    f16x8 bhf[4], blf[4], ahf[4], alf[4];                                           \
    RD_B(CUR, 0); RD_A(CUR, 0, 0);                                                  \
    PRIO1; MM(0, 0, 0); PRIO0;                                                      \
    RD_A(CUR, 1, 1);                                                                \
    CVT_LO(NXT, RCVT);                               /* A(KT+1) lower -> buf[NXT] */\
    PRIO1; MM(1, 1, 0); PRIO0;                                                      \
    RD_B(CUR, 1);                                                                   \
    CVT_HI(NXT, RCVT);                               /* A(KT+1) upper */            \
    PRIO1; MM(0, 0, 1); MM(1, 1, 1); PRIO0;                                         \
    RD_A(CUR, 2, 2);                                                                \
    LOAD_A(RLOAD, nk2);                              /* A(KT+2) -> regs */          \
    PRIO1; MM(2, 2, 0); MM(2, 2, 1); PRIO0;                                         \
    RD_A(CUR, 3, 3);                                                                \
    PRIO1; MM(3, 3, 0); MM(3, 3, 1); PRIO0;                                         \
    RD_B(CUR, 2);                                                                   \
    STAGE_B(NXT, 2, wh, nk1);                                                       \
    PRIO1; MM(0, 0, 2); MM(1, 1, 2); MM(2, 2, 2); MM(3, 3, 2); PRIO0;               \
    RD_B(CUR, 3);                                                                   \
    STAGE_B(NXT, 3, wl, nk1);                                                       \
    PRIO1; MM(0, 0, 3); MM(1, 1, 3); MM(2, 2, 3); MM(3, 3, 3); PRIO0;               \
    RD_A(CUR, 0, 4);                                                                \
    PRIO1; MM(0, 4, 0); MM(0, 4, 1); MM(0, 4, 2); MM(0, 4, 3); PRIO0;               \
    RD_A(CUR, 1, 5);                                                                \
    PRIO1; MM(1, 5, 0); MM(1, 5, 1); MM(1, 5, 2); MM(1, 5, 3); PRIO0;               \
    RD_A(CUR, 2, 6);                                                                \
    PRIO1; MM(2, 6, 0); MM(2, 6, 1); MM(2, 6, 2); MM(2, 6, 3); PRIO0;               \
    RD_A(CUR, 3, 7);                                                                \
    PRIO1; MM(3, 7, 0); MM(3, 7, 1); MM(3, 7, 2); MM(3, 7, 3); PRIO0;               \
    asm volatile("s_waitcnt lgkmcnt(0)" ::: "memory"); /* cvt writes (older) done */\
    asm volatile("" ::: "memory");                                                  \
    __builtin_amdgcn_s_barrier(); /* all waves done reading buf[CUR] */             \
  } while (0)

  for (int kt2 = 0; kt2 < 16; ++kt2) {
    KBODY(2 * kt2,     0, 1, regA, regB);  // even: cvt regB=A(odd) -> buf1, load A(k+2)->regA
    KBODY(2 * kt2 + 1, 1, 0, regB, regA);  // odd : cvt regA -> buf0,        load -> regB
  }
#undef KBODY
#undef RD_B
#undef RD_A
#undef MM
#undef PRIO1
#undef PRIO0
#undef STAGE_B
#undef LOAD_A
#undef CVT_LO
#undef CVT_HI

  // ======== fused epilogue: relu + GEMM2-partial + stats (no hbuf) ========
  asm volatile("s_waitcnt vmcnt(0)" ::: "memory");  // drain in-flight loads
  __syncthreads();                                  // LDS now free for reuse
  float* vt = (float*)&lds[0][0][0];                // [256 rows][128 cols f32], granule-swizzled

  // E0: bias + relu in place
#pragma unroll
  for (int j = 0; j < 4; ++j) {
    const float bias = b1[n0 + wc + j * 16 + lr];
#pragma unroll
    for (int i = 0; i < 8; ++i)
#pragma unroll
      for (int r = 0; r < 4; ++r) acc[i][j][r] = fmaxf(acc[i][j][r] + bias, 0.f);
  }

  f32x4 acc2[2] = {};
  float sstat[2] = {0.f, 0.f}, qstat[2] = {0.f, 0.f};
  const int myrow0 = w * 32;  // reader rows: [w*32, w*32+32)

#pragma unroll
  for (int half = 0; half < 2; ++half) {
    // write phase: waves with (w&3)>>1 == half own cols [half*128, half*128+128)
    if (((w & 3) >> 1) == half) {
      const int colbase = wc & 127;
#pragma unroll
      for (int j = 0; j < 4; ++j) {
        const int lcol = colbase + j * 16 + lr;
        const int g = lcol >> 2, wsel = lcol & 3;
#pragma unroll
        for (int i = 0; i < 8; ++i)
#pragma unroll
          for (int r = 0; r < 4; ++r) {
            const int row = wr + i * 16 + lg * 4 + r;
            vt[row * 128 + ((g ^ (row & 7)) << 2) + wsel] = acc[i][j][r];
          }
      }
    }
    __syncthreads();
    // read phase: 4 k-blocks of 32 cols
#pragma unroll
    for (int cl = 0; cl < 4; ++cl) {
      const int cglob = (n0 >> 5) + half * 4 + cl;
      const f16x8 bh = *(const f16x8*)(fh + (size_t)(cglob * 64 + lane) * 8);
      const f16x8 bl = *(const f16x8*)(fl + (size_t)(cglob * 64 + lane) * 8);
#pragma unroll
      for (int g2 = 0; g2 < 2; ++g2) {
        const int row = myrow0 + g2 * 16 + lr;
        const int g0 = cl * 8 + lg * 2;
        const float4 f0 = *(const float4*)&vt[row * 128 + ((g0 ^ (row & 7)) << 2)];
        const float4 f1 = *(const float4*)&vt[row * 128 + (((g0 + 1) ^ (row & 7)) << 2)];
        float f[8] = {f0.x, f0.y, f0.z, f0.w, f1.x, f1.y, f1.z, f1.w};
        f16x8 AH, AL;
#pragma unroll
        for (int e = 0; e < 8; ++e) {
          sstat[g2] += f[e];
          qstat[g2] = fmaf(f[e], f[e], qstat[g2]);
          _Float16 hi = (_Float16)f[e];
          AH[e] = hi;
          AL[e] = (_Float16)(f[e] - (float)hi);
        }
        acc2[g2] = MFMA_F16(AH, bh, acc2[g2]);
        acc2[g2] = MFMA_F16(AH, bl, acc2[g2]);
        acc2[g2] = MFMA_F16(AL, bh, acc2[g2]);
      }
    }
    __syncthreads();
  }

  // stats reduce over the 4 lg-lanes (same lr = same row)
#pragma unroll
  for (int g2 = 0; g2 < 2; ++g2) {
    sstat[g2] += __shfl_xor(sstat[g2], 16, 64);
    sstat[g2] += __shfl_xor(sstat[g2], 32, 64);
    qstat[g2] += __shfl_xor(qstat[g2], 16, 64);
    qstat[g2] += __shfl_xor(qstat[g2], 32, 64);
  }
  const int ntile = n0 >> 8;
#pragma unroll
  for (int g2 = 0; g2 < 2; ++g2) {
    if (lg == 0) {
      const int row = m0 + myrow0 + g2 * 16 + lr;
      *(float2*)&pstat[((size_t)row * 8 + ntile) * 2] = make_float2(sstat[g2], qstat[g2]);
    }
    if (lr < 9) {
#pragma unroll
      for (int r = 0; r < 4; ++r) {
        const int row = m0 + myrow0 + g2 * 16 + lg * 4 + r;
        pdot[((size_t)row * 8 + ntile) * 12 + lr] = acc2[g2][r];
      }
    }
  }
}

// ---------------- f64 3x3 SVD -> nearest SO(3) rotation ----------------
static __device__ __forceinline__ void jrot(double S[3][3], double V[3][3], int p, int q, int r) {
  double apq = S[p][q];
  if (apq == 0.0) return;
  double tau = (S[q][q] - S[p][p]) / (2.0 * apq);
  double t = (tau >= 0.0 ? 1.0 : -1.0) / (fabs(tau) + sqrt(1.0 + tau * tau));
  double c = 1.0 / sqrt(1.0 + t * t);
  double s = t * c;
  double spp = S[p][p], sqq = S[q][q];
  double srp = S[r][p], srq = S[r][q];
  S[p][p] = spp - t * apq;
  S[q][q] = sqq + t * apq;
  S[p][q] = 0.0; S[q][p] = 0.0;
  S[r][p] = c * srp - s * srq; S[p][r] = S[r][p];
  S[r][q] = s * srp + c * srq; S[q][r] = S[r][q];
#pragma unroll
  for (int i = 0; i < 3; ++i) {
    double vip = V[i][p], viq = V[i][q];
    V[i][p] = c * vip - s * viq;
    V[i][q] = s * vip + c * viq;
  }
}

static __device__ void svd_so3(const double* Rf, float* Of) {
  double A[3][3], S[3][3];
  double V[3][3] = {{1, 0, 0}, {0, 1, 0}, {0, 0, 1}};
#pragma unroll
  for (int i = 0; i < 3; ++i)
#pragma unroll
    for (int j = 0; j < 3; ++j) A[i][j] = Rf[i * 3 + j];
#pragma unroll
  for (int p = 0; p < 3; ++p)
#pragma unroll
    for (int q = 0; q < 3; ++q) {
      double sa = 0.0;
#pragma unroll
      for (int i = 0; i < 3; ++i) sa += A[i][p] * A[i][q];
      S[p][q] = sa;
    }
  for (int it = 0; it < 6; ++it) {
    jrot(S, V, 0, 1, 2);
    jrot(S, V, 0, 2, 1);
    jrot(S, V, 1, 2, 0);
  }
  double l0 = S[0][0], l1 = S[1][1], l2 = S[2][2];
  double c0[3] = {V[0][0], V[1][0], V[2][0]};
  double c1[3] = {V[0][1], V[1][1], V[2][1]};
  double c2[3] = {V[0][2], V[1][2], V[2][2]};
  double tl, tv;
#define SWP(la, lb, ca, cb)                                         \
  if (la < lb) {                                                    \
    tl = la; la = lb; lb = tl;                                      \
    tv = ca[0]; ca[0] = cb[0]; cb[0] = tv;                          \
    tv = ca[1]; ca[1] = cb[1]; cb[1] = tv;                          \
    tv = ca[2]; ca[2] = cb[2]; cb[2] = tv;                          \
  }
  SWP(l0, l1, c0, c1)
  SWP(l0, l2, c0, c2)
  SWP(l1, l2, c1, c2)
#undef SWP
  double v3[3];
  v3[0] = c0[1] * c1[2] - c0[2] * c1[1];
  v3[1] = c0[2] * c1[0] - c0[0] * c1[2];
  v3[2] = c0[0] * c1[1] - c0[1] * c1[0];
  double t1[3], t2[3];
#pragma unroll
  for (int i = 0; i < 3; ++i) {
    t1[i] = A[i][0] * c0[0] + A[i][1] * c0[1] + A[i][2] * c0[2];
    t2[i] = A[i][0] * c1[0] + A[i][1] * c1[1] + A[i][2] * c1[2];
  }
  double n1 = sqrt(t1[0] * t1[0] + t1[1] * t1[1] + t1[2] * t1[2]);
  if (n1 < 1e-20) {
#pragma unroll
    for (int t = 0; t < 9; ++t) Of[t] = (t == 0 || t == 4 || t == 8) ? 1.f : 0.f;
    return;
  }
  double u1[3], u2[3], u3[3];
  double r1 = 1.0 / n1;
#pragma unroll
  for (int i = 0; i < 3; ++i) u1[i] = t1[i] * r1;
  double d12 = u1[0] * t2[0] + u1[1] * t2[1] + u1[2] * t2[2];
#pragma unroll
  for (int i = 0; i < 3; ++i) t2[i] -= d12 * u1[i];
  double n2 = sqrt(t2[0] * t2[0] + t2[1] * t2[1] + t2[2] * t2[2]);
  if (n2 > 1e-14 * n1) {
    double r2 = 1.0 / n2;
#pragma unroll
    for (int i = 0; i < 3; ++i) u2[i] = t2[i] * r2;
  } else {
    double ax = fabs(u1[0]), ay = fabs(u1[1]), az = fabs(u1[2]);
    double e[3] = {0.0, 0.0, 0.0};
    if (ax <= ay && ax <= az) e[0] = 1.0;
    else if (ay <= az) e[1] = 1.0;
    else e[2] = 1.0;
    double d = e[0] * u1[0] + e[1] * u1[1] + e[2] * u1[2];
#pragma unroll
    for (int i = 0; i < 3; ++i) e[i] -= d * u1[i];
    double nn = 1.0 / sqrt(e[0] * e[0] + e[1] * e[1] + e[2] * e[2]);
#pragma unroll
    for (int i = 0; i < 3; ++i) u2[i] = e[i] * nn;
  }
  u3[0] = u1[1] * u2[2] - u1[2] * u2[1];
  u3[1] = u1[2] * u2[0] - u1[0] * u2[2];
  u3[2] = u1[0] * u2[1] - u1[1] * u2[0];
#pragma unroll
  for (int i = 0; i < 3; ++i)
#pragma unroll
    for (int j = 0; j < 3; ++j)
      Of[i * 3 + j] = (float)(u1[i] * c0[j] + u2[i] * c1[j] + u3[i] * v3[j]);
}

// ---------------- combine: f64 sum of partials + LN1-fold + LN2 + SVD, 1 thread/row ----------------
__global__ __launch_bounds__(256) void k_comb(const float* __restrict__ pdot,
                                              const float* __restrict__ pstat,
                                              const double* __restrict__ cgcb,
                                              const float* __restrict__ b2,
                                              const float* __restrict__ g2v,
                                              const float* __restrict__ be2,
                                              float* __restrict__ out) {
  const int row = blockIdx.x * 256 + threadIdx.x;
  double dj[9];
#pragma unroll
  for (int j = 0; j < 9; ++j) dj[j] = 0.0;
  double s = 0.0, q = 0.0;
#pragma unroll
  for (int nt = 0; nt < 8; ++nt) {
    const float* p = pdot + ((size_t)row * 8 + nt) * 12;
#pragma unroll
    for (int j = 0; j < 9; ++j) dj[j] += (double)p[j];
    const float* ps = pstat + ((size_t)row * 8 + nt) * 2;
    s += (double)ps[0];
    q += (double)ps[1];
  }
  const double mean = s * (1.0 / 2048.0);
  const double varr = fmax(q * (1.0 / 2048.0) - mean * mean, 0.0);
  const double inv = 1.0 / sqrt(varr + 1e-5);
  double a2[9];
  double s9 = 0.0, q9 = 0.0;
#pragma unroll
  for (int j = 0; j < 9; ++j) {
    double v = inv * (dj[j] - mean * cgcb[j]) + cgcb[16 + j] + (double)b2[j];
    v = fmax(v, 0.0);
    a2[j] = v;
    s9 += v;
    q9 += v * v;
  }
  const double m2 = s9 * (1.0 / 9.0);
  const double v2c = fmax(q9 * (1.0 / 9.0) - m2 * m2, 0.0);
  const double i2 = 1.0 / sqrt(v2c + 1e-5);
  double rn[9];
#pragma unroll
  for (int j = 0; j < 9; ++j) rn[j] = (a2[j] - m2) * i2 * (double)g2v[j] + (double)be2[j];
  float O[9];
  svd_so3(rn, O);
  float* op = out + (size_t)row * 9;
#pragma unroll
  for (int t = 0; t < 9; ++t) op[t] = O[t];
}

// ---------------- host ----------------
extern "C" void kernel_launch(void* const* d_in, const int* in_sizes, int n_in,
                              void* d_out, int out_size, void* d_ws, size_t ws_size,
                              hipStream_t stream) {
  const float* x   = (const float*)d_in[0];
  const float* W1  = (const float*)d_in[1];
  const float* b1  = (const float*)d_in[2];
  const float* g1  = (const float*)d_in[3];
  const float* be1 = (const float*)d_in[4];
  const float* W2  = (const float*)d_in[5];
  const float* b2  = (const float*)d_in[6];
  const float* g2  = (const float*)d_in[7];
  const float* be2 = (const float*)d_in[8];
  float* out = (float*)d_out;
  char* ws = (char*)d_ws;
  u16*    wh   = (u16*)(ws + 0);             // 4194304
  u16*    wl   = (u16*)(ws + 4194304);       // 4194304
  u16*    fh   = (u16*)(ws + 8388608);       // 65536
  u16*    fl   = (u16*)(ws + 8454144);       // 65536
  double* cgcb = (double*)(ws + 8519680);    // 256 B
  float*  pdot = (float*)(ws + 8519936);     // 32768*8*12*4 = 12582912
  float*  pstat= (float*)(ws + 21102848);    // 32768*8*2*4  = 2097152

  k_split_w1t<<<dim3(2048), dim3(256), 0, stream>>>(W1, wh, wl);
  k_w2frag<<<dim3(16), dim3(256), 0, stream>>>(W2, g1, fh, fl);
  k_cgcb<<<dim3(1), dim3(64), 0, stream>>>(W2, g1, be1, cgcb);
  k_gemm1<<<dim3(1024), dim3(512), 0, stream>>>(x, wh, wl, b1, fh, fl, pdot, pstat);
  k_comb<<<dim3(128), dim3(256), 0, stream>>>(pdot, pstat, cgcb, b2, g2, be2, out);
}